// Round 3
// baseline (487.551 us; speedup 1.0000x reference)
//
#include <hip/hip_runtime.h>

typedef __attribute__((ext_vector_type(8))) short   short8;
typedef __attribute__((ext_vector_type(8))) __bf16  bf16x8;
typedef __attribute__((ext_vector_type(4))) float   f32x4;

#define NSTEPS 49

static __device__ __forceinline__ short8 as_s8(bf16x8 v) {
    return __builtin_bit_cast(short8, v);
}

#define MFMA(A, B, C) __builtin_amdgcn_mfma_f32_16x16x32_bf16((A), (B), (C), 0, 0, 0)

// Re-class a weight fragment into the AGPR file (zero instructions; the MFMA
// A-operand reads AGPRs directly on gfx950, freeing architected VGPRs).
#define PIN_AGPR(x) asm("" : "+a"(x))

// xs slices from f32x4 SRC[4]: slice0[j] = SRC[j>>2][j&3], slice1[j] = SRC[(j>>2)+2][j&3]
#define BUILD_XS(SRC)                                                        \
    {                                                                        \
        bf16x8 v0_, v1_;                                                     \
        _Pragma("unroll")                                                    \
        for (int j_ = 0; j_ < 8; ++j_) {                                     \
            v0_[j_] = (__bf16)(SRC)[j_ >> 2][j_ & 3];                        \
            v1_[j_] = (__bf16)(SRC)[(j_ >> 2) + 2][j_ & 3];                  \
        }                                                                    \
        xs0 = as_s8(v0_); xs1 = as_s8(v1_);                                  \
    }

// Third L1 K-slice: k=64 carries t, k=65 carries constant 1.0 (bias column).
#define BUILD_XT(TV)                                                         \
    {                                                                        \
        bf16x8 v_;                                                           \
        _Pragma("unroll") for (int j_ = 0; j_ < 8; ++j_) v_[j_] = (__bf16)0.f; \
        if (q == 0) { v_[0] = (__bf16)(TV); v_[1] = (__bf16)1.0f; }          \
        xt = as_s8(v_);                                                      \
    }

// Store fresh f32 k (f32x4[4]) as packed bf16 in xs-slice order (8 VGPRs).
#define STORE_KB(KB, KV)                                                     \
    {                                                                        \
        bf16x8 t0_, t1_;                                                     \
        _Pragma("unroll")                                                    \
        for (int j_ = 0; j_ < 8; ++j_) {                                     \
            t0_[j_] = (__bf16)(KV)[j_ >> 2][j_ & 3];                         \
            t1_[j_] = (__bf16)(KV)[(j_ >> 2) + 2][j_ & 3];                   \
        }                                                                    \
        (KB)[0] = t0_; (KB)[1] = t1_;                                        \
    }

// Unpack one bf16 k value (V = 0..15, compile-time in unrolled loops).
#define KF(KB, V) ((float)(KB)[(V) >> 3][(V) & 7])

// Full 3-layer MLP in registers. Biases enter as the MFMA C-operand init
// (f32, zero VALU cost). Output KV[t][r] = k[c][16t+4q+r] (f32).
#define MLP_EVAL(KV)                                                         \
    {                                                                        \
        const f32x4 zz_ = {0.f, 0.f, 0.f, 0.f};                              \
        short8 xh_[4];                                                       \
        _Pragma("unroll")                                                    \
        for (int ks_ = 0; ks_ < 4; ++ks_) {                                  \
            f32x4 aA_ = MFMA(wA0[2*ks_  ][0], xs0, zz_);                     \
            aA_ = MFMA(wA0[2*ks_  ][1], xs1, aA_);                           \
            aA_ = MFMA(wA0[2*ks_  ][2], xt,  aA_);                           \
            f32x4 aB_ = MFMA(wA0[2*ks_+1][0], xs0, zz_);                     \
            aB_ = MFMA(wA0[2*ks_+1][1], xs1, aB_);                           \
            aB_ = MFMA(wA0[2*ks_+1][2], xt,  aB_);                           \
            bf16x8 v_;                                                       \
            v_[0] = (__bf16)fmaxf(aA_[0], 0.f);                              \
            v_[1] = (__bf16)fmaxf(aA_[1], 0.f);                              \
            v_[2] = (__bf16)fmaxf(aA_[2], 0.f);                              \
            v_[3] = (__bf16)fmaxf(aA_[3], 0.f);                              \
            v_[4] = (__bf16)fmaxf(aB_[0], 0.f);                              \
            v_[5] = (__bf16)fmaxf(aB_[1], 0.f);                              \
            v_[6] = (__bf16)fmaxf(aB_[2], 0.f);                              \
            v_[7] = (__bf16)fmaxf(aB_[3], 0.f);                              \
            xh_[ks_] = as_s8(v_);                                            \
        }                                                                    \
        short8 xg_[4];                                                       \
        _Pragma("unroll")                                                    \
        for (int ks_ = 0; ks_ < 4; ++ks_) {                                  \
            f32x4 aA_ = MFMA(wA1[2*ks_  ][0], xh_[0], bL2v[2*ks_  ]);        \
            aA_ = MFMA(wA1[2*ks_  ][1], xh_[1], aA_);                        \
            aA_ = MFMA(wA1[2*ks_  ][2], xh_[2], aA_);                        \
            aA_ = MFMA(wA1[2*ks_  ][3], xh_[3], aA_);                        \
            f32x4 aB_ = MFMA(wA1[2*ks_+1][0], xh_[0], bL2v[2*ks_+1]);        \
            aB_ = MFMA(wA1[2*ks_+1][1], xh_[1], aB_);                        \
            aB_ = MFMA(wA1[2*ks_+1][2], xh_[2], aB_);                        \
            aB_ = MFMA(wA1[2*ks_+1][3], xh_[3], aB_);                        \
            bf16x8 v_;                                                       \
            v_[0] = (__bf16)fmaxf(aA_[0], 0.f);                              \
            v_[1] = (__bf16)fmaxf(aA_[1], 0.f);                              \
            v_[2] = (__bf16)fmaxf(aA_[2], 0.f);                              \
            v_[3] = (__bf16)fmaxf(aA_[3], 0.f);                              \
            v_[4] = (__bf16)fmaxf(aB_[0], 0.f);                              \
            v_[5] = (__bf16)fmaxf(aB_[1], 0.f);                              \
            v_[6] = (__bf16)fmaxf(aB_[2], 0.f);                              \
            v_[7] = (__bf16)fmaxf(aB_[3], 0.f);                              \
            xg_[ks_] = as_s8(v_);                                            \
        }                                                                    \
        _Pragma("unroll")                                                    \
        for (int t_ = 0; t_ < 4; ++t_) {                                     \
            f32x4 ac_ = MFMA(wA2[t_][0], xg_[0], bL3v[t_]);                  \
            ac_ = MFMA(wA2[t_][1], xg_[1], ac_);                             \
            ac_ = MFMA(wA2[t_][2], xg_[2], ac_);                             \
            ac_ = MFMA(wA2[t_][3], xg_[3], ac_);                             \
            KV[t_] = ac_;                                                    \
        }                                                                    \
    }

// One wave per block owns 16 batch rows and the entire MLP.
// wA0+wA1 (224 regs) are pinned into the AGPR file via empty inline asm with
// an "a" constraint (gfx950 MFMA reads A-operands from AGPR directly) — this
// is the fix for R1/R2's ~10 MB/launch scratch spill (compiler never used
// AGPRs on its own; VGPR demand 288+state > 256 architected -> scratch).
// wA2 (64) + state stay VGPR-side (~235 peak < 256). k0..k4 kept as packed
// bf16; 5th-order y-update accumulates fresh f32 k's. Zero LDS, zero
// barriers, zero shuffles.
extern "C" __global__ void __launch_bounds__(64, 1)
node_solve(const float* __restrict__ y0, const float* __restrict__ ts,
           const float* __restrict__ gw0, const float* __restrict__ gb0,
           const float* __restrict__ gw1, const float* __restrict__ gb1,
           const float* __restrict__ gw2, const float* __restrict__ gb2,
           float* __restrict__ out)
{
    const int lane = threadIdx.x & 63;
    const int q    = lane >> 4;
    const int c    = lane & 15;
    const int row0 = blockIdx.x << 4;

    // ---- weights -> K-permuted register A-frags ----
    // perm: k-position 32ks+8q+j  <-  source column 32ks+16*(j>>2)+4q+(j&3)
    short8 wA0[8][3];   // L1: 128 neurons x K=96 (y dims + [t, bias-1] slice) -> AGPR
    short8 wA1[8][4];   // L2: 128 x 128                                      -> AGPR
    short8 wA2[4][4];   // L3: 64 x 128                                       -> VGPR
    f32x4  bL2v[8], bL3v[4];   // bias C-init vectors, layout b[16t+4q+r]

    #pragma unroll
    for (int t = 0; t < 8; ++t) {
        const int n = 16 * t + c;
        const float* w0r = gw0 + n * 65 + 1;      // col 0 of gw0 is the t-weight
        #pragma unroll
        for (int ks = 0; ks < 2; ++ks) {
            bf16x8 v;
            #pragma unroll
            for (int j = 0; j < 8; ++j)
                v[j] = (__bf16)w0r[32*ks + 16*(j>>2) + 4*q + (j&3)];
            short8 sv = as_s8(v);
            PIN_AGPR(sv);
            wA0[t][ks] = sv;
        }
        {
            bf16x8 v;
            #pragma unroll
            for (int j = 0; j < 8; ++j) v[j] = (__bf16)0.f;
            if (q == 0) { v[0] = (__bf16)gw0[n*65]; v[1] = (__bf16)gb0[n]; }
            short8 sv = as_s8(v);
            PIN_AGPR(sv);
            wA0[t][2] = sv;
        }
        const float* w1r = gw1 + n * 128;
        #pragma unroll
        for (int ks = 0; ks < 4; ++ks) {
            bf16x8 v;
            #pragma unroll
            for (int j = 0; j < 8; ++j)
                v[j] = (__bf16)w1r[32*ks + 16*(j>>2) + 4*q + (j&3)];
            short8 sv = as_s8(v);
            PIN_AGPR(sv);
            wA1[t][ks] = sv;
        }
        bL2v[t] = *(const f32x4*)(gb1 + 16*t + 4*q);
    }
    #pragma unroll
    for (int t = 0; t < 4; ++t) {
        const int n = 16 * t + c;
        const float* w2r = gw2 + n * 128;
        #pragma unroll
        for (int ks = 0; ks < 4; ++ks) {
            bf16x8 v;
            #pragma unroll
            for (int j = 0; j < 8; ++j)
                v[j] = (__bf16)w2r[32*ks + 16*(j>>2) + 4*q + (j&3)];
            wA2[t][ks] = as_s8(v);
        }
        bL3v[t] = *(const f32x4*)(gb2 + 16*t + 4*q);
    }

    // ---- persistent state: y[t][r] = y[row0+c][16t+4q+r] ----
    f32x4 y[4];
    #pragma unroll
    for (int t = 0; t < 4; ++t)
        y[t] = *(const f32x4*)(y0 + (size_t)(row0 + c) * 64 + 16*t + 4*q);

    const float ts0 = ts[0];
    const float dtv = ts[1] - ts[0];

    // dt-scaled Tsit5 tableau (hoisted scalars; wave-uniform -> SGPRs)
    const float d21 = dtv * 0.161f;
    const float d31 = dtv * -0.008480655492356989f, d32 = dtv * 0.335480655492357f;
    const float d41 = dtv * 2.8971530571054935f,  d42 = dtv * -6.359448489975075f,  d43 = dtv * 4.3622954328695815f;
    const float d51 = dtv * 5.325864828439257f,   d52 = dtv * -11.748883564062828f, d53 = dtv * 7.4955393428898365f, d54 = dtv * -0.09249506636175525f;
    const float d61 = dtv * 5.86145544294642f,    d62 = dtv * -12.92096931784711f,  d63 = dtv * 8.159367898576159f,  d64 = dtv * -0.071584973281401f, d65 = dtv * -0.028269050394068383f;
    const float e1  = dtv * 0.09646076681806523f, e2  = dtv * 0.01f,                e3  = dtv * 0.4798896504144996f;
    const float e4  = dtv * 1.379008574103742f,   e5  = dtv * -3.290069515436081f,  e6  = dtv * 2.324710524099774f;

    short8 xs0, xs1, xt;

    #pragma unroll 1
    for (int step = 0; step < NSTEPS; ++step) {
        const float t0s = ts0 + (float)step * dtv;
        f32x4 kv[4], si[4], yn[4];
        bf16x8 kb0[2], kb1[2], kb2[2], kb3[2], kb4[2];

        // ---- stage 1 ----
        BUILD_XS(y); BUILD_XT(t0s);
        MLP_EVAL(kv);
        #pragma unroll
        for (int t = 0; t < 4; ++t) yn[t] = y[t] + e1 * kv[t];
        STORE_KB(kb0, kv);

        // ---- stage 2 ----
        #pragma unroll
        for (int v = 0; v < 16; ++v)
            si[v>>2][v&3] = y[v>>2][v&3] + d21*KF(kb0,v);
        BUILD_XS(si); BUILD_XT(t0s + 0.161f * dtv);
        MLP_EVAL(kv);
        #pragma unroll
        for (int t = 0; t < 4; ++t) yn[t] += e2 * kv[t];
        STORE_KB(kb1, kv);

        // ---- stage 3 ----
        #pragma unroll
        for (int v = 0; v < 16; ++v)
            si[v>>2][v&3] = y[v>>2][v&3] + d31*KF(kb0,v) + d32*KF(kb1,v);
        BUILD_XS(si); BUILD_XT(t0s + 0.327f * dtv);
        MLP_EVAL(kv);
        #pragma unroll
        for (int t = 0; t < 4; ++t) yn[t] += e3 * kv[t];
        STORE_KB(kb2, kv);

        // ---- stage 4 ----
        #pragma unroll
        for (int v = 0; v < 16; ++v)
            si[v>>2][v&3] = y[v>>2][v&3] + d41*KF(kb0,v) + d42*KF(kb1,v) + d43*KF(kb2,v);
        BUILD_XS(si); BUILD_XT(t0s + 0.9f * dtv);
        MLP_EVAL(kv);
        #pragma unroll
        for (int t = 0; t < 4; ++t) yn[t] += e4 * kv[t];
        STORE_KB(kb3, kv);

        // ---- stage 5 ----
        #pragma unroll
        for (int v = 0; v < 16; ++v)
            si[v>>2][v&3] = y[v>>2][v&3] + d51*KF(kb0,v) + d52*KF(kb1,v) + d53*KF(kb2,v) + d54*KF(kb3,v);
        BUILD_XS(si); BUILD_XT(t0s + 0.9800255409045097f * dtv);
        MLP_EVAL(kv);
        #pragma unroll
        for (int t = 0; t < 4; ++t) yn[t] += e5 * kv[t];
        STORE_KB(kb4, kv);

        // ---- stage 6 ----
        #pragma unroll
        for (int v = 0; v < 16; ++v)
            si[v>>2][v&3] = y[v>>2][v&3] + d61*KF(kb0,v) + d62*KF(kb1,v) + d63*KF(kb2,v) + d64*KF(kb3,v) + d65*KF(kb4,v);
        BUILD_XS(si); BUILD_XT(t0s + dtv);
        MLP_EVAL(kv);
        #pragma unroll
        for (int t = 0; t < 4; ++t) y[t] = yn[t] + e6 * kv[t];
    }

    #pragma unroll
    for (int t = 0; t < 4; ++t)
        *(f32x4*)(out + (size_t)(row0 + c) * 64 + 16*t + 4*q) = y[t];
}

extern "C" void kernel_launch(void* const* d_in, const int* in_sizes, int n_in,
                              void* d_out, int out_size, void* d_ws, size_t ws_size,
                              hipStream_t stream) {
    const float* y0 = (const float*)d_in[0];
    const float* ts = (const float*)d_in[1];
    const float* w0 = (const float*)d_in[2];
    const float* b0 = (const float*)d_in[3];
    const float* w1 = (const float*)d_in[4];
    const float* b1 = (const float*)d_in[5];
    const float* w2 = (const float*)d_in[6];
    const float* b2 = (const float*)d_in[7];
    float* out = (float*)d_out;

    node_solve<<<dim3(128), dim3(64), 0, stream>>>(y0, ts, w0, b0, w1, b1, w2, b2, out);
}

// Round 4
// 433.718 us; speedup vs baseline: 1.1241x; 1.1241x over previous
//
#include <hip/hip_runtime.h>

typedef __attribute__((ext_vector_type(8))) short   short8;
typedef __attribute__((ext_vector_type(8))) __bf16  bf16x8;
typedef __attribute__((ext_vector_type(4))) float   f32x4;

#define NSTEPS 49

static __device__ __forceinline__ short8 as_s8(bf16x8 v) {
    return __builtin_bit_cast(short8, v);
}

#define MFMA(A, B, C) __builtin_amdgcn_mfma_f32_16x16x32_bf16((A), (B), (C), 0, 0, 0)

// Weight fragment indices in LDS:
//   L1 tile t (0..7), slice ks (0..2):  t*3 + ks      (ks==2 is the [t,bias] column pair)
//   L2 tile t (0..7), slice ks (0..3):  24 + t*4 + ks
//   L3 tile t (0..3), slice ks (0..3):  56 + t*4 + ks
#define NFRAG 72

// xs slices from f32x4 SRC[4]: slice0[j] = SRC[j>>2][j&3], slice1[j] = SRC[(j>>2)+2][j&3]
#define BUILD_XS(SRC)                                                        \
    {                                                                        \
        bf16x8 v0_, v1_;                                                     \
        _Pragma("unroll")                                                    \
        for (int j_ = 0; j_ < 8; ++j_) {                                     \
            v0_[j_] = (__bf16)(SRC)[j_ >> 2][j_ & 3];                        \
            v1_[j_] = (__bf16)(SRC)[(j_ >> 2) + 2][j_ & 3];                  \
        }                                                                    \
        xs0 = as_s8(v0_); xs1 = as_s8(v1_);                                  \
    }

// Third L1 K-slice: k=64 carries t, k=65 carries constant 1.0 (bias column).
#define BUILD_XT(TV)                                                         \
    {                                                                        \
        bf16x8 v_;                                                           \
        _Pragma("unroll") for (int j_ = 0; j_ < 8; ++j_) v_[j_] = (__bf16)0.f; \
        if (q == 0) { v_[0] = (__bf16)(TV); v_[1] = (__bf16)1.0f; }          \
        xt = as_s8(v_);                                                      \
    }

// Store fresh f32 k (f32x4[4]) as packed bf16 in xs-slice order (8 VGPRs).
#define STORE_KB(KB, KV)                                                     \
    {                                                                        \
        bf16x8 t0_, t1_;                                                     \
        _Pragma("unroll")                                                    \
        for (int j_ = 0; j_ < 8; ++j_) {                                     \
            t0_[j_] = (__bf16)(KV)[j_ >> 2][j_ & 3];                         \
            t1_[j_] = (__bf16)(KV)[(j_ >> 2) + 2][j_ & 3];                   \
        }                                                                    \
        (KB)[0] = t0_; (KB)[1] = t1_;                                        \
    }

// Unpack one bf16 k value (V = 0..15, compile-time in unrolled loops).
#define KF(KB, V) ((float)(KB)[(V) >> 3][(V) & 7])

// Weight-fragment LDS read. fz is laundered to 0-but-opaque each MLP eval so
// GVN/LICM cannot hoist the (loop-invariant) reads into ~288 registers and
// recreate the R1-R3 scratch spill. Addressing folds to one base + imm offset.
#define LW(IDX) (Wlds[fz + (unsigned)(IDX)][lane])

// Full 3-layer MLP; weights streamed from LDS (72 x ds_read_b128 per eval),
// activations/state in registers. Biases enter as MFMA C-operand init.
// Output KV[t][r] = k[c][16t+4q+r] (f32).
#define MLP_EVAL(KV)                                                         \
    {                                                                        \
        asm volatile("" : "+v"(fz));                                         \
        const f32x4 zz_ = {0.f, 0.f, 0.f, 0.f};                              \
        short8 xh_[4];                                                       \
        _Pragma("unroll")                                                    \
        for (int ks_ = 0; ks_ < 4; ++ks_) {                                  \
            f32x4 aA_ = MFMA(LW(3*(2*ks_) + 0), xs0, zz_);                   \
            aA_ = MFMA(LW(3*(2*ks_) + 1), xs1, aA_);                         \
            aA_ = MFMA(LW(3*(2*ks_) + 2), xt,  aA_);                         \
            f32x4 aB_ = MFMA(LW(3*(2*ks_+1) + 0), xs0, zz_);                 \
            aB_ = MFMA(LW(3*(2*ks_+1) + 1), xs1, aB_);                       \
            aB_ = MFMA(LW(3*(2*ks_+1) + 2), xt,  aB_);                       \
            bf16x8 v_;                                                       \
            v_[0] = (__bf16)fmaxf(aA_[0], 0.f);                              \
            v_[1] = (__bf16)fmaxf(aA_[1], 0.f);                              \
            v_[2] = (__bf16)fmaxf(aA_[2], 0.f);                              \
            v_[3] = (__bf16)fmaxf(aA_[3], 0.f);                              \
            v_[4] = (__bf16)fmaxf(aB_[0], 0.f);                              \
            v_[5] = (__bf16)fmaxf(aB_[1], 0.f);                              \
            v_[6] = (__bf16)fmaxf(aB_[2], 0.f);                              \
            v_[7] = (__bf16)fmaxf(aB_[3], 0.f);                              \
            xh_[ks_] = as_s8(v_);                                            \
        }                                                                    \
        short8 xg_[4];                                                       \
        _Pragma("unroll")                                                    \
        for (int ks_ = 0; ks_ < 4; ++ks_) {                                  \
            f32x4 aA_ = MFMA(LW(24 + 4*(2*ks_) + 0), xh_[0], bL2v[2*ks_  ]); \
            aA_ = MFMA(LW(24 + 4*(2*ks_) + 1), xh_[1], aA_);                 \
            aA_ = MFMA(LW(24 + 4*(2*ks_) + 2), xh_[2], aA_);                 \
            aA_ = MFMA(LW(24 + 4*(2*ks_) + 3), xh_[3], aA_);                 \
            f32x4 aB_ = MFMA(LW(24 + 4*(2*ks_+1) + 0), xh_[0], bL2v[2*ks_+1]);\
            aB_ = MFMA(LW(24 + 4*(2*ks_+1) + 1), xh_[1], aB_);               \
            aB_ = MFMA(LW(24 + 4*(2*ks_+1) + 2), xh_[2], aB_);               \
            aB_ = MFMA(LW(24 + 4*(2*ks_+1) + 3), xh_[3], aB_);               \
            bf16x8 v_;                                                       \
            v_[0] = (__bf16)fmaxf(aA_[0], 0.f);                              \
            v_[1] = (__bf16)fmaxf(aA_[1], 0.f);                              \
            v_[2] = (__bf16)fmaxf(aA_[2], 0.f);                              \
            v_[3] = (__bf16)fmaxf(aA_[3], 0.f);                              \
            v_[4] = (__bf16)fmaxf(aB_[0], 0.f);                              \
            v_[5] = (__bf16)fmaxf(aB_[1], 0.f);                              \
            v_[6] = (__bf16)fmaxf(aB_[2], 0.f);                              \
            v_[7] = (__bf16)fmaxf(aB_[3], 0.f);                              \
            xg_[ks_] = as_s8(v_);                                            \
        }                                                                    \
        _Pragma("unroll")                                                    \
        for (int t_ = 0; t_ < 4; ++t_) {                                     \
            f32x4 ac_ = MFMA(LW(56 + 4*t_ + 0), xg_[0], bL3v[t_]);           \
            ac_ = MFMA(LW(56 + 4*t_ + 1), xg_[1], ac_);                      \
            ac_ = MFMA(LW(56 + 4*t_ + 2), xg_[2], ac_);                      \
            ac_ = MFMA(LW(56 + 4*t_ + 3), xg_[3], ac_);                      \
            KV[t_] = ac_;                                                    \
        }                                                                    \
    }

// One wave per block owns 16 batch rows and the entire MLP. Weights live in
// LDS as per-lane fragments (Wlds[frag][lane], 16B/lane: a wave's read is 64
// contiguous 16B = conflict-free) and are streamed each stage — this removes
// the 288-reg weight pressure that caused R1-R3's scratch spills. State stays
// in registers (~230 VGPR). Zero barriers in the loop, zero shuffles.
extern "C" __global__ void __launch_bounds__(64, 1)
node_solve(const float* __restrict__ y0, const float* __restrict__ ts,
           const float* __restrict__ gw0, const float* __restrict__ gb0,
           const float* __restrict__ gw1, const float* __restrict__ gb1,
           const float* __restrict__ gw2, const float* __restrict__ gb2,
           float* __restrict__ out)
{
    __shared__ short8 Wlds[NFRAG][64];   // 72 KiB

    const int lane = threadIdx.x & 63;
    const int q    = lane >> 4;
    const int c    = lane & 15;
    const int row0 = blockIdx.x << 4;

    // ---- stage weights into LDS as K-permuted per-lane A-frags ----
    // perm: k-position 32ks+8q+j  <-  source column 32ks+16*(j>>2)+4q+(j&3)
    for (int t = 0; t < 8; ++t) {
        const int n = 16 * t + c;
        const float* w0r = gw0 + n * 65 + 1;      // col 0 of gw0 is the t-weight
        for (int ks = 0; ks < 2; ++ks) {
            bf16x8 v;
            #pragma unroll
            for (int j = 0; j < 8; ++j)
                v[j] = (__bf16)w0r[32*ks + 16*(j>>2) + 4*q + (j&3)];
            Wlds[t*3 + ks][lane] = as_s8(v);
        }
        {
            bf16x8 v;
            #pragma unroll
            for (int j = 0; j < 8; ++j) v[j] = (__bf16)0.f;
            if (q == 0) { v[0] = (__bf16)gw0[n*65]; v[1] = (__bf16)gb0[n]; }
            Wlds[t*3 + 2][lane] = as_s8(v);
        }
        const float* w1r = gw1 + n * 128;
        for (int ks = 0; ks < 4; ++ks) {
            bf16x8 v;
            #pragma unroll
            for (int j = 0; j < 8; ++j)
                v[j] = (__bf16)w1r[32*ks + 16*(j>>2) + 4*q + (j&3)];
            Wlds[24 + t*4 + ks][lane] = as_s8(v);
        }
    }
    for (int t = 0; t < 4; ++t) {
        const int n = 16 * t + c;
        const float* w2r = gw2 + n * 128;
        for (int ks = 0; ks < 4; ++ks) {
            bf16x8 v;
            #pragma unroll
            for (int j = 0; j < 8; ++j)
                v[j] = (__bf16)w2r[32*ks + 16*(j>>2) + 4*q + (j&3)];
            Wlds[56 + t*4 + ks][lane] = as_s8(v);
        }
    }
    __syncthreads();   // single wave: compiles to a waitcnt (+barrier), once

    // ---- resident biases (C-operand init vectors), layout b[16t+4q+r] ----
    f32x4 bL2v[8], bL3v[4];
    #pragma unroll
    for (int t = 0; t < 8; ++t) bL2v[t] = *(const f32x4*)(gb1 + 16*t + 4*q);
    #pragma unroll
    for (int t = 0; t < 4; ++t) bL3v[t] = *(const f32x4*)(gb2 + 16*t + 4*q);

    // ---- persistent state: y[t][r] = y[row0+c][16t+4q+r] ----
    f32x4 y[4];
    #pragma unroll
    for (int t = 0; t < 4; ++t)
        y[t] = *(const f32x4*)(y0 + (size_t)(row0 + c) * 64 + 16*t + 4*q);

    const float ts0 = ts[0];
    const float dtv = ts[1] - ts[0];

    // dt-scaled Tsit5 tableau (hoisted scalars; wave-uniform -> SGPRs)
    const float d21 = dtv * 0.161f;
    const float d31 = dtv * -0.008480655492356989f, d32 = dtv * 0.335480655492357f;
    const float d41 = dtv * 2.8971530571054935f,  d42 = dtv * -6.359448489975075f,  d43 = dtv * 4.3622954328695815f;
    const float d51 = dtv * 5.325864828439257f,   d52 = dtv * -11.748883564062828f, d53 = dtv * 7.4955393428898365f, d54 = dtv * -0.09249506636175525f;
    const float d61 = dtv * 5.86145544294642f,    d62 = dtv * -12.92096931784711f,  d63 = dtv * 8.159367898576159f,  d64 = dtv * -0.071584973281401f, d65 = dtv * -0.028269050394068383f;
    const float e1  = dtv * 0.09646076681806523f, e2  = dtv * 0.01f,                e3  = dtv * 0.4798896504144996f;
    const float e4  = dtv * 1.379008574103742f,   e5  = dtv * -3.290069515436081f,  e6  = dtv * 2.324710524099774f;

    short8 xs0, xs1, xt;
    unsigned fz = 0;   // laundered per MLP eval; always 0, provably unknowable

    #pragma unroll 1
    for (int step = 0; step < NSTEPS; ++step) {
        const float t0s = ts0 + (float)step * dtv;
        f32x4 kv[4], si[4], yn[4];
        bf16x8 kb0[2], kb1[2], kb2[2], kb3[2], kb4[2];

        // ---- stage 1 ----
        BUILD_XS(y); BUILD_XT(t0s);
        MLP_EVAL(kv);
        #pragma unroll
        for (int t = 0; t < 4; ++t) yn[t] = y[t] + e1 * kv[t];
        STORE_KB(kb0, kv);

        // ---- stage 2 ----
        #pragma unroll
        for (int v = 0; v < 16; ++v)
            si[v>>2][v&3] = y[v>>2][v&3] + d21*KF(kb0,v);
        BUILD_XS(si); BUILD_XT(t0s + 0.161f * dtv);
        MLP_EVAL(kv);
        #pragma unroll
        for (int t = 0; t < 4; ++t) yn[t] += e2 * kv[t];
        STORE_KB(kb1, kv);

        // ---- stage 3 ----
        #pragma unroll
        for (int v = 0; v < 16; ++v)
            si[v>>2][v&3] = y[v>>2][v&3] + d31*KF(kb0,v) + d32*KF(kb1,v);
        BUILD_XS(si); BUILD_XT(t0s + 0.327f * dtv);
        MLP_EVAL(kv);
        #pragma unroll
        for (int t = 0; t < 4; ++t) yn[t] += e3 * kv[t];
        STORE_KB(kb2, kv);

        // ---- stage 4 ----
        #pragma unroll
        for (int v = 0; v < 16; ++v)
            si[v>>2][v&3] = y[v>>2][v&3] + d41*KF(kb0,v) + d42*KF(kb1,v) + d43*KF(kb2,v);
        BUILD_XS(si); BUILD_XT(t0s + 0.9f * dtv);
        MLP_EVAL(kv);
        #pragma unroll
        for (int t = 0; t < 4; ++t) yn[t] += e4 * kv[t];
        STORE_KB(kb3, kv);

        // ---- stage 5 ----
        #pragma unroll
        for (int v = 0; v < 16; ++v)
            si[v>>2][v&3] = y[v>>2][v&3] + d51*KF(kb0,v) + d52*KF(kb1,v) + d53*KF(kb2,v) + d54*KF(kb3,v);
        BUILD_XS(si); BUILD_XT(t0s + 0.9800255409045097f * dtv);
        MLP_EVAL(kv);
        #pragma unroll
        for (int t = 0; t < 4; ++t) yn[t] += e5 * kv[t];
        STORE_KB(kb4, kv);

        // ---- stage 6 ----
        #pragma unroll
        for (int v = 0; v < 16; ++v)
            si[v>>2][v&3] = y[v>>2][v&3] + d61*KF(kb0,v) + d62*KF(kb1,v) + d63*KF(kb2,v) + d64*KF(kb3,v) + d65*KF(kb4,v);
        BUILD_XS(si); BUILD_XT(t0s + dtv);
        MLP_EVAL(kv);
        #pragma unroll
        for (int t = 0; t < 4; ++t) y[t] = yn[t] + e6 * kv[t];
    }

    #pragma unroll
    for (int t = 0; t < 4; ++t)
        *(f32x4*)(out + (size_t)(row0 + c) * 64 + 16*t + 4*q) = y[t];
}

extern "C" void kernel_launch(void* const* d_in, const int* in_sizes, int n_in,
                              void* d_out, int out_size, void* d_ws, size_t ws_size,
                              hipStream_t stream) {
    const float* y0 = (const float*)d_in[0];
    const float* ts = (const float*)d_in[1];
    const float* w0 = (const float*)d_in[2];
    const float* b0 = (const float*)d_in[3];
    const float* w1 = (const float*)d_in[4];
    const float* b1 = (const float*)d_in[5];
    const float* w2 = (const float*)d_in[6];
    const float* b2 = (const float*)d_in[7];
    float* out = (float*)d_out;

    node_solve<<<dim3(128), dim3(64), 0, stream>>>(y0, ts, w0, b0, w1, b1, w2, b2, out);
}

// Round 5
// 388.421 us; speedup vs baseline: 1.2552x; 1.1166x over previous
//
#include <hip/hip_runtime.h>

typedef __attribute__((ext_vector_type(8))) short   short8;
typedef __attribute__((ext_vector_type(8))) __bf16  bf16x8;
typedef __attribute__((ext_vector_type(4))) float   f32x4;

#define NSTEPS 49

static __device__ __forceinline__ short8 as_s8(bf16x8 v) {
    return __builtin_bit_cast(short8, v);
}

#define MFMA(A, B, C) __builtin_amdgcn_mfma_f32_16x16x32_bf16((A), (B), (C), 0, 0, 0)

// Weight fragment indices in LDS (all unit bases consecutive):
//   L1 unit u (0..3): frags 6u..6u+5   (tiles 2u,2u+1 x 3 slices; slice 2 = [t,bias])
//   L2 unit u (0..3): frags 24+8u..24+8u+7
//   L3 unit m (0..1): frags 56+8m..56+8m+7
#define NFRAG 72

// Laundered-base LDS frag read (fz == 0 but opaque per eval: blocks cross-eval
// CSE that would hoist 288 regs of weights and recreate the R1-R3 spills).
#define LW(IDX) (Wlds[fz + (unsigned)(IDX)][lane])

// Bank loads (issued one unit ahead of use -> ~150 cyc prefetch distance).
#define LD_A6(F0) { pA0=LW((F0)+0); pA1=LW((F0)+1); pA2=LW((F0)+2);          \
                    pA3=LW((F0)+3); pA4=LW((F0)+4); pA5=LW((F0)+5); }
#define LD_B6(F0) { pB0=LW((F0)+0); pB1=LW((F0)+1); pB2=LW((F0)+2);          \
                    pB3=LW((F0)+3); pB4=LW((F0)+4); pB5=LW((F0)+5); }
#define LD_A8(F0) { LD_A6(F0); pA6=LW((F0)+6); pA7=LW((F0)+7); }
#define LD_B8(F0) { LD_B6(F0); pB6=LW((F0)+6); pB7=LW((F0)+7); }

#define RELU_PACK(AA, AB, OUT)                                               \
    {                                                                        \
        bf16x8 v_;                                                           \
        v_[0]=(__bf16)fmaxf((AA)[0],0.f); v_[1]=(__bf16)fmaxf((AA)[1],0.f);  \
        v_[2]=(__bf16)fmaxf((AA)[2],0.f); v_[3]=(__bf16)fmaxf((AA)[3],0.f);  \
        v_[4]=(__bf16)fmaxf((AB)[0],0.f); v_[5]=(__bf16)fmaxf((AB)[1],0.f);  \
        v_[6]=(__bf16)fmaxf((AB)[2],0.f); v_[7]=(__bf16)fmaxf((AB)[3],0.f);  \
        OUT = as_s8(v_);                                                     \
    }

#define L1_UNIT(W0,W1,W2,W3,W4,W5,OUT)                                       \
    {                                                                        \
        f32x4 aA_ = MFMA(W0, xs0, zz); aA_ = MFMA(W1, xs1, aA_);             \
        aA_ = MFMA(W2, xt, aA_);                                             \
        f32x4 aB_ = MFMA(W3, xs0, zz); aB_ = MFMA(W4, xs1, aB_);             \
        aB_ = MFMA(W5, xt, aB_);                                             \
        RELU_PACK(aA_, aB_, OUT);                                            \
    }

#define L2_UNIT(W0,W1,W2,W3,W4,W5,W6,W7,CA,CB,OUT)                           \
    {                                                                        \
        f32x4 aA_ = MFMA(W0, xh0, CA); aA_ = MFMA(W1, xh1, aA_);             \
        aA_ = MFMA(W2, xh2, aA_);      aA_ = MFMA(W3, xh3, aA_);             \
        f32x4 aB_ = MFMA(W4, xh0, CB); aB_ = MFMA(W5, xh1, aB_);             \
        aB_ = MFMA(W6, xh2, aB_);      aB_ = MFMA(W7, xh3, aB_);             \
        RELU_PACK(aA_, aB_, OUT);                                            \
    }

#define L3_UNIT(W0,W1,W2,W3,W4,W5,W6,W7,CA,CB,OA,OB)                         \
    {                                                                        \
        f32x4 aA_ = MFMA(W0, xg0, CA); aA_ = MFMA(W1, xg1, aA_);             \
        aA_ = MFMA(W2, xg2, aA_);      aA_ = MFMA(W3, xg3, aA_);             \
        f32x4 aB_ = MFMA(W4, xg0, CB); aB_ = MFMA(W5, xg1, aB_);             \
        aB_ = MFMA(W6, xg2, aB_);      aB_ = MFMA(W7, xg3, aB_);             \
        OA = aA_; OB = aB_;                                                  \
    }

// 10-unit software-pipelined MLP eval: unit i+1's LDS loads issue before
// unit i's MFMAs (double-banked pA/pB), so every ds_read_b128 has ~150 cyc
// of independent work before first use. Tail prefetches next eval's unit 0
// (covered by the inter-stage state-update VALU).
#define MLP_EVAL(KV)                                                         \
    {                                                                        \
        const f32x4 zz = {0.f, 0.f, 0.f, 0.f};                               \
        short8 xh0, xh1, xh2, xh3, xg0, xg1, xg2, xg3;                       \
        LD_B6(6);  L1_UNIT(pA0,pA1,pA2,pA3,pA4,pA5, xh0);                    \
        LD_A6(12); L1_UNIT(pB0,pB1,pB2,pB3,pB4,pB5, xh1);                    \
        LD_B6(18); L1_UNIT(pA0,pA1,pA2,pA3,pA4,pA5, xh2);                    \
        LD_A8(24); L1_UNIT(pB0,pB1,pB2,pB3,pB4,pB5, xh3);                    \
        LD_B8(32); L2_UNIT(pA0,pA1,pA2,pA3,pA4,pA5,pA6,pA7,                  \
                           bL2v[0], bL2v[1], xg0);                           \
        LD_A8(40); L2_UNIT(pB0,pB1,pB2,pB3,pB4,pB5,pB6,pB7,                  \
                           bL2v[2], bL2v[3], xg1);                           \
        LD_B8(48); L2_UNIT(pA0,pA1,pA2,pA3,pA4,pA5,pA6,pA7,                  \
                           bL2v[4], bL2v[5], xg2);                           \
        LD_A8(56); L2_UNIT(pB0,pB1,pB2,pB3,pB4,pB5,pB6,pB7,                  \
                           bL2v[6], bL2v[7], xg3);                           \
        LD_B8(64); L3_UNIT(pA0,pA1,pA2,pA3,pA4,pA5,pA6,pA7,                  \
                           bL3v[0], bL3v[1], KV[0], KV[1]);                  \
        asm volatile("" : "+v"(fz));                                         \
        LD_A6(0);  /* next eval unit 0 */                                    \
        L3_UNIT(pB0,pB1,pB2,pB3,pB4,pB5,pB6,pB7,                             \
                bL3v[2], bL3v[3], KV[2], KV[3]);                             \
    }

// xs slices from f32x4 SRC[4]: slice0[j] = SRC[j>>2][j&3], slice1[j] = SRC[(j>>2)+2][j&3]
#define BUILD_XS(SRC)                                                        \
    {                                                                        \
        bf16x8 v0_, v1_;                                                     \
        _Pragma("unroll")                                                    \
        for (int j_ = 0; j_ < 8; ++j_) {                                     \
            v0_[j_] = (__bf16)(SRC)[j_ >> 2][j_ & 3];                        \
            v1_[j_] = (__bf16)(SRC)[(j_ >> 2) + 2][j_ & 3];                  \
        }                                                                    \
        xs0 = as_s8(v0_); xs1 = as_s8(v1_);                                  \
    }

// Third L1 K-slice: k=64 carries t, k=65 carries constant 1.0 (bias column).
#define BUILD_XT(TV)                                                         \
    {                                                                        \
        bf16x8 v_;                                                           \
        _Pragma("unroll") for (int j_ = 0; j_ < 8; ++j_) v_[j_] = (__bf16)0.f; \
        if (q == 0) { v_[0] = (__bf16)(TV); v_[1] = (__bf16)1.0f; }          \
        xt = as_s8(v_);                                                      \
    }

// Store fresh f32 k (f32x4[4]) as packed bf16 in xs-slice order (8 VGPRs).
#define STORE_KB(KB, KV)                                                     \
    {                                                                        \
        bf16x8 t0_, t1_;                                                     \
        _Pragma("unroll")                                                    \
        for (int j_ = 0; j_ < 8; ++j_) {                                     \
            t0_[j_] = (__bf16)(KV)[j_ >> 2][j_ & 3];                         \
            t1_[j_] = (__bf16)(KV)[(j_ >> 2) + 2][j_ & 3];                   \
        }                                                                    \
        (KB)[0] = t0_; (KB)[1] = t1_;                                        \
    }

// Unpack one bf16 k value (V = 0..15, compile-time in unrolled loops).
#define KF(KB, V) ((float)(KB)[(V) >> 3][(V) & 7])

// One wave per block owns 16 batch rows and the entire MLP. Weights stream
// from LDS (Wlds[frag][lane], 16B/lane, conflict-free) through a depth-1
// register pipeline. State is reparametrized against the running 5th-order
// accumulator yn (si_s = yn + sum (a_sj - b_j) k_j), which removes y[] and
// kb4 (fresh k always used in f32). Zero barriers in the loop, zero shuffles.
extern "C" __global__ void __launch_bounds__(64, 1)
node_solve(const float* __restrict__ y0, const float* __restrict__ ts,
           const float* __restrict__ gw0, const float* __restrict__ gb0,
           const float* __restrict__ gw1, const float* __restrict__ gb1,
           const float* __restrict__ gw2, const float* __restrict__ gb2,
           float* __restrict__ out)
{
    __shared__ short8 Wlds[NFRAG][64];   // 72 KiB

    const int lane = threadIdx.x & 63;
    const int q    = lane >> 4;
    const int c    = lane & 15;
    const int row0 = blockIdx.x << 4;

    // ---- stage weights into LDS as K-permuted per-lane A-frags ----
    // perm: k-position 32ks+8q+j  <-  source column 32ks+16*(j>>2)+4q+(j&3)
    for (int t = 0; t < 8; ++t) {
        const int n = 16 * t + c;
        const float* w0r = gw0 + n * 65 + 1;      // col 0 of gw0 is the t-weight
        for (int ks = 0; ks < 2; ++ks) {
            bf16x8 v;
            #pragma unroll
            for (int j = 0; j < 8; ++j)
                v[j] = (__bf16)w0r[32*ks + 16*(j>>2) + 4*q + (j&3)];
            Wlds[t*3 + ks][lane] = as_s8(v);   // note: frag layout below
        }
        {
            bf16x8 v;
            #pragma unroll
            for (int j = 0; j < 8; ++j) v[j] = (__bf16)0.f;
            if (q == 0) { v[0] = (__bf16)gw0[n*65]; v[1] = (__bf16)gb0[n]; }
            Wlds[t*3 + 2][lane] = as_s8(v);
        }
        const float* w1r = gw1 + n * 128;
        for (int ks = 0; ks < 4; ++ks) {
            bf16x8 v;
            #pragma unroll
            for (int j = 0; j < 8; ++j)
                v[j] = (__bf16)w1r[32*ks + 16*(j>>2) + 4*q + (j&3)];
            Wlds[24 + t*4 + ks][lane] = as_s8(v);
        }
    }
    for (int t = 0; t < 4; ++t) {
        const int n = 16 * t + c;
        const float* w2r = gw2 + n * 128;
        for (int ks = 0; ks < 4; ++ks) {
            bf16x8 v;
            #pragma unroll
            for (int j = 0; j < 8; ++j)
                v[j] = (__bf16)w2r[32*ks + 16*(j>>2) + 4*q + (j&3)];
            Wlds[56 + t*4 + ks][lane] = as_s8(v);
        }
    }
    __syncthreads();   // single wave: once, before the loop

    // ---- resident biases (C-operand init vectors), layout b[16t+4q+r] ----
    f32x4 bL2v[8], bL3v[4];
    #pragma unroll
    for (int t = 0; t < 8; ++t) bL2v[t] = *(const f32x4*)(gb1 + 16*t + 4*q);
    #pragma unroll
    for (int t = 0; t < 4; ++t) bL3v[t] = *(const f32x4*)(gb2 + 16*t + 4*q);

    // ---- persistent state: yn[t][r] = y[row0+c][16t+4q+r] (running 5th-order sum) ----
    f32x4 yn[4];
    #pragma unroll
    for (int t = 0; t < 4; ++t)
        yn[t] = *(const f32x4*)(y0 + (size_t)(row0 + c) * 64 + 16*t + 4*q);

    const float ts0 = ts[0];
    const float dtv = ts[1] - ts[0];

    // dt-scaled b-weights and reparametrized stage coefficients g_sj = a_sj - b_j
    const float e1 = dtv * 0.09646076681806523f, e2 = dtv * 0.01f;
    const float e3 = dtv * 0.4798896504144996f,  e4 = dtv * 1.379008574103742f;
    const float e5 = dtv * -3.290069515436081f,  e6 = dtv * 2.324710524099774f;
    const float g21 = dtv * (0.161f                 - 0.09646076681806523f);
    const float g31 = dtv * (-0.008480655492356989f - 0.09646076681806523f);
    const float g32 = dtv * (0.335480655492357f     - 0.01f);
    const float g41 = dtv * (2.8971530571054935f    - 0.09646076681806523f);
    const float g42 = dtv * (-6.359448489975075f    - 0.01f);
    const float g43 = dtv * (4.3622954328695815f    - 0.4798896504144996f);
    const float g51 = dtv * (5.325864828439257f     - 0.09646076681806523f);
    const float g52 = dtv * (-11.748883564062828f   - 0.01f);
    const float g53 = dtv * (7.4955393428898365f    - 0.4798896504144996f);
    const float g54 = dtv * (-0.09249506636175525f  - 1.379008574103742f);
    const float g61 = dtv * (5.86145544294642f      - 0.09646076681806523f);
    const float g62 = dtv * (-12.92096931784711f    - 0.01f);
    const float g63 = dtv * (8.159367898576159f     - 0.4798896504144996f);
    const float g64 = dtv * (-0.071584973281401f    - 1.379008574103742f);
    const float g65 = dtv * (-0.028269050394068383f + 3.290069515436081f);

    short8 xs0, xs1, xt;
    short8 pA0, pA1, pA2, pA3, pA4, pA5, pA6, pA7;
    short8 pB0, pB1, pB2, pB3, pB4, pB5, pB6, pB7;
    unsigned fz = 0;   // laundered per MLP eval; always 0, provably unknowable

    // initial prefetch of eval 0's unit 0
    asm volatile("" : "+v"(fz));
    LD_A6(0);

    #pragma unroll 1
    for (int step = 0; step < NSTEPS; ++step) {
        const float t0s = ts0 + (float)step * dtv;
        f32x4 kv[4], si[4];
        bf16x8 kb0[2], kb1[2], kb2[2], kb3[2];

        // ---- stage 1 ----
        BUILD_XS(yn); BUILD_XT(t0s);
        MLP_EVAL(kv);
        #pragma unroll
        for (int t = 0; t < 4; ++t) yn[t] += e1 * kv[t];
        STORE_KB(kb0, kv);

        // ---- stage 2 (fresh k0 in f32) ----
        #pragma unroll
        for (int t = 0; t < 4; ++t) si[t] = yn[t] + g21 * kv[t];
        BUILD_XS(si); BUILD_XT(t0s + 0.161f * dtv);
        MLP_EVAL(kv);
        #pragma unroll
        for (int t = 0; t < 4; ++t) yn[t] += e2 * kv[t];
        STORE_KB(kb1, kv);

        // ---- stage 3 ----
        #pragma unroll
        for (int v = 0; v < 16; ++v)
            si[v>>2][v&3] = yn[v>>2][v&3] + g31*KF(kb0,v) + g32*kv[v>>2][v&3];
        BUILD_XS(si); BUILD_XT(t0s + 0.327f * dtv);
        MLP_EVAL(kv);
        #pragma unroll
        for (int t = 0; t < 4; ++t) yn[t] += e3 * kv[t];
        STORE_KB(kb2, kv);

        // ---- stage 4 ----
        #pragma unroll
        for (int v = 0; v < 16; ++v)
            si[v>>2][v&3] = yn[v>>2][v&3] + g41*KF(kb0,v) + g42*KF(kb1,v)
                          + g43*kv[v>>2][v&3];
        BUILD_XS(si); BUILD_XT(t0s + 0.9f * dtv);
        MLP_EVAL(kv);
        #pragma unroll
        for (int t = 0; t < 4; ++t) yn[t] += e4 * kv[t];
        STORE_KB(kb3, kv);

        // ---- stage 5 ----
        #pragma unroll
        for (int v = 0; v < 16; ++v)
            si[v>>2][v&3] = yn[v>>2][v&3] + g51*KF(kb0,v) + g52*KF(kb1,v)
                          + g53*KF(kb2,v) + g54*kv[v>>2][v&3];
        BUILD_XS(si); BUILD_XT(t0s + 0.9800255409045097f * dtv);
        MLP_EVAL(kv);
        #pragma unroll
        for (int t = 0; t < 4; ++t) yn[t] += e5 * kv[t];

        // ---- stage 6 (fresh k4 in f32; no kb4 needed) ----
        #pragma unroll
        for (int v = 0; v < 16; ++v)
            si[v>>2][v&3] = yn[v>>2][v&3] + g61*KF(kb0,v) + g62*KF(kb1,v)
                          + g63*KF(kb2,v) + g64*KF(kb3,v) + g65*kv[v>>2][v&3];
        BUILD_XS(si); BUILD_XT(t0s + dtv);
        MLP_EVAL(kv);
        #pragma unroll
        for (int t = 0; t < 4; ++t) yn[t] += e6 * kv[t];
    }

    #pragma unroll
    for (int t = 0; t < 4; ++t)
        *(f32x4*)(out + (size_t)(row0 + c) * 64 + 16*t + 4*q) = yn[t];
}

extern "C" void kernel_launch(void* const* d_in, const int* in_sizes, int n_in,
                              void* d_out, int out_size, void* d_ws, size_t ws_size,
                              hipStream_t stream) {
    const float* y0 = (const float*)d_in[0];
    const float* ts = (const float*)d_in[1];
    const float* w0 = (const float*)d_in[2];
    const float* b0 = (const float*)d_in[3];
    const float* w1 = (const float*)d_in[4];
    const float* b1 = (const float*)d_in[5];
    const float* w2 = (const float*)d_in[6];
    const float* b2 = (const float*)d_in[7];
    float* out = (float*)d_out;

    node_solve<<<dim3(128), dim3(64), 0, stream>>>(y0, ts, w0, b0, w1, b1, w2, b2, out);
}